// Round 9
// baseline (270.222 us; speedup 1.0000x reference)
//
#include <hip/hip_runtime.h>
#include <math.h>

#define F 128
#define FIX_SCALE 16777216.0f          // 2^24
#define FIX_INV   (1.0f / 16777216.0f)
#define CNT_SHIFT 40
#define DEG_MASK  ((1ULL << 40) - 1)
#define PSTRIDE 8                      // packed counter stride: 8 ull = 64 B/line

using bf16x8 = __attribute__((ext_vector_type(8))) short;
using f32x4  = __attribute__((ext_vector_type(4))) float;

// ---------- helpers ----------
__device__ inline int read_idx(const int* ei, long long elem, int i64) {
    return i64 ? (int)((const long long*)ei)[elem] : ei[elem];
}
__device__ inline unsigned int f2bf_rn(float f) {   // fp32 -> bf16 bits, RNE
    unsigned int b = __float_as_uint(f);
    return (b + 0x7FFFu + ((b >> 16) & 1u)) >> 16;
}
__device__ inline float bflo(unsigned int u) { return __uint_as_float(u << 16); }
__device__ inline float bfhi(unsigned int u) { return __uint_as_float(u & 0xFFFF0000u); }

// ---------- K1: zero padded packed counters, detect index dtype ----------
__global__ void k_init(unsigned long long* packed, int* flag, const int* ei, int M8) {
    int i = blockIdx.x * blockDim.x + threadIdx.x;
    if (i < M8) packed[i] = 0ULL;
    if (i == 0) {
        int i64 = 1;
        for (int j = 0; j < 32; ++j) if (ei[2 * j + 1] != 0) { i64 = 0; break; }
        *flag = i64;
    }
}

// ---------- K2: one packed 64-bit atomic per edge (64B-padded counters) ----------
__global__ void k_count(const int* ei, const float* ew, unsigned long long* packed,
                        unsigned short* pos, const int* flag, int E) {
    int e = blockIdx.x * blockDim.x + threadIdx.x;
    if (e >= E) return;
    int i64 = *flag;
    int c = read_idx(ei, (long long)E + e, i64);
    unsigned long long u = (1ULL << CNT_SHIFT) |
                           (unsigned long long)(ew[e] * FIX_SCALE + 0.5f);
    unsigned long long old = atomicAdd(&packed[(size_t)c * PSTRIDE], u);
    pos[e] = (unsigned short)(old >> CNT_SHIFT);
}

// ---------- K3a: per-block sums of cnt ----------
__global__ void k_bsum(const unsigned long long* __restrict__ packed,
                       int* __restrict__ bsum, int N) {
    __shared__ int s[4];
    int i = blockIdx.x * 256 + threadIdx.x;
    int v = (i < N) ? (int)(packed[(size_t)i * PSTRIDE] >> CNT_SHIFT) : 0;
    #pragma unroll
    for (int o = 1; o < 64; o <<= 1) v += __shfl_xor(v, o, 64);
    if ((threadIdx.x & 63) == 0) s[threadIdx.x >> 6] = v;
    __syncthreads();
    if (threadIdx.x == 0) bsum[blockIdx.x] = s[0] + s[1] + s[2] + s[3];
}

// ---------- K3b: off = exclusive CSR offsets (self-prefixed); dinv = rsqrt(1+deg) ----------
__global__ void k_offs2(const unsigned long long* __restrict__ packed,
                        const int* __restrict__ bsum,
                        int* __restrict__ off, float* __restrict__ dinv, int N, int E) {
    __shared__ int sred[256];
    __shared__ int sdata[256];
    int t = threadIdx.x;
    int pre = 0;
    for (int j = t; j < blockIdx.x; j += 256) pre += bsum[j];
    sred[t] = pre;
    __syncthreads();
    #pragma unroll
    for (int s = 128; s > 0; s >>= 1) {
        if (t < s) sred[t] += sred[t + s];
        __syncthreads();
    }
    int base = sred[0];
    int i = blockIdx.x * 256 + t;
    unsigned long long p = (i < N) ? packed[(size_t)i * PSTRIDE] : 0ULL;
    int v = (int)(p >> CNT_SHIFT);
    sdata[t] = v;
    __syncthreads();
    #pragma unroll
    for (int s = 1; s < 256; s <<= 1) {
        int add = (t >= s) ? sdata[t - s] : 0;
        __syncthreads();
        sdata[t] += add;
        __syncthreads();
    }
    if (i < N) {
        off[i] = base + sdata[t] - v;  // exclusive
        float deg = 1.0f + (float)(p & DEG_MASK) * FIX_INV;  // +1 self-loop
        dinv[i] = rsqrtf(deg);
        if (i == N - 1) off[N] = E;
    }
}

// ---------- K4: cast xs = bf16(dinv*x) + evolve W (independent, blockIdx-ranged) ----------
__global__ __launch_bounds__(256) void k_ce(
        const float2* __restrict__ x2, const float* __restrict__ dinv,
        unsigned int* __restrict__ xs, int M, int nCastBlk,
        const float* __restrict__ W0, const float* __restrict__ Wih,
        const float* __restrict__ Whh, const float* __restrict__ bih,
        const float* __restrict__ bhh,
        unsigned short* __restrict__ Wth, unsigned short* __restrict__ Wtl) {
    int b = blockIdx.x;
    if (b < nCastBlk) {
        int id = b * 256 + threadIdx.x;
        if (id < M) {
            float di = dinv[id >> 6];
            float2 v = x2[id];
            xs[id] = f2bf_rn(di * v.x) | (f2bf_rn(di * v.y) << 16);
        }
        return;
    }
    b -= nCastBlk;
    // evolve: 2 rows of W per block (256 threads = 2 x 128)
    __shared__ __align__(16) float w0row[2][F];
    int half = threadIdx.x >> 7;
    int i = b * 2 + half;           // k index (row of W)
    int j = threadIdx.x & 127;      // n index (col of W)
    w0row[half][j] = W0[i * F + j];
    __syncthreads();
    float air = 0, aiz = 0, ain = 0, ahr = 0, ahz = 0, ahn = 0;
    const float* ir_p = Wih + (size_t)j * F;
    const float* iz_p = Wih + (size_t)(j + F) * F;
    const float* in_p = Wih + (size_t)(j + 2 * F) * F;
    const float* hr_p = Whh + (size_t)j * F;
    const float* hz_p = Whh + (size_t)(j + F) * F;
    const float* hn_p = Whh + (size_t)(j + 2 * F) * F;
    for (int k = 0; k < F; k += 4) {
        float4 w0 = *(const float4*)&w0row[half][k];
        float4 a;
        a = *(const float4*)&ir_p[k]; air += w0.x*a.x + w0.y*a.y + w0.z*a.z + w0.w*a.w;
        a = *(const float4*)&iz_p[k]; aiz += w0.x*a.x + w0.y*a.y + w0.z*a.z + w0.w*a.w;
        a = *(const float4*)&in_p[k]; ain += w0.x*a.x + w0.y*a.y + w0.z*a.z + w0.w*a.w;
        a = *(const float4*)&hr_p[k]; ahr += w0.x*a.x + w0.y*a.y + w0.z*a.z + w0.w*a.w;
        a = *(const float4*)&hz_p[k]; ahz += w0.x*a.x + w0.y*a.y + w0.z*a.z + w0.w*a.w;
        a = *(const float4*)&hn_p[k]; ahn += w0.x*a.x + w0.y*a.y + w0.z*a.z + w0.w*a.w;
    }
    air += bih[j];         ahr += bhh[j];
    aiz += bih[j + F];     ahz += bhh[j + F];
    ain += bih[j + 2*F];   ahn += bhh[j + 2*F];
    float r = 1.0f / (1.0f + expf(-(air + ahr)));
    float z = 1.0f / (1.0f + expf(-(aiz + ahz)));
    float n = tanhf(ain + r * ahn);
    float w = (1.0f - z) * n + z * w0row[half][j];
    unsigned int hb = f2bf_rn(w);
    float whi = __uint_as_float(hb << 16);
    unsigned int lb = f2bf_rn(w - whi);
    Wth[j * F + i] = (unsigned short)hb;   // transposed: Wt[n][k]
    Wtl[j * F + i] = (unsigned short)lb;
}

// ---------- K5: placement, packed 4B edge = (row<<16) | w16 ----------
__global__ void k_place(const int* ei, const float* ew,
                        const int* __restrict__ off,
                        const unsigned short* __restrict__ pos,
                        unsigned int* ep32, const int* flag, int E) {
    int e = blockIdx.x * blockDim.x + threadIdx.x;
    if (e >= E) return;
    int i64 = *flag;
    int r = read_idx(ei, e, i64);
    int c = read_idx(ei, (long long)E + e, i64);
    unsigned int w16 = (unsigned int)(ew[e] * 65536.0f);
    if (w16 > 65535u) w16 = 65535u;
    ep32[off[c] + (int)pos[e]] = ((unsigned int)r << 16) | w16;  // requires N < 65536
}

// ---------- K6: aggregation, 1 node/wave; UNIFORM shfl participation ----------
// Per 64-edge chunk: every lane loads one edge, then 4 fully-unrolled rounds in
// which ALL 64 lanes execute the shfls (sources always EXEC-active); only the
// gather/FMA uses are guarded (group-uniform branches, no cross-lane ops inside).
__global__ __launch_bounds__(256) void k_agg2(const uint4* __restrict__ xs4,
                                              const int* __restrict__ off,
                                              const unsigned int* __restrict__ ep32,
                                              const float* __restrict__ dinv,
                                              uint4* __restrict__ hagg4, int N) {
    int wave = threadIdx.x >> 6, lane = threadIdx.x & 63;
    int c = blockIdx.x * 4 + wave;
    if (c >= N) return;
    int g = lane >> 4, sl = lane & 15;
    int start = off[c], end = off[c + 1];
    int deg = end - start;

    float a0[8] = {0,0,0,0,0,0,0,0}, a1[8] = {0,0,0,0,0,0,0,0};
    if (g == 0) {   // self-loop (raw weight 1): xs row of c
        uint4 v = xs4[(size_t)c * 16 + sl];
        a0[0] = bflo(v.x); a0[1] = bfhi(v.x);
        a0[2] = bflo(v.y); a0[3] = bfhi(v.y);
        a0[4] = bflo(v.z); a0[5] = bfhi(v.z);
        a0[6] = bflo(v.w); a0[7] = bfhi(v.w);
    }
    for (int base = 0; base < deg; base += 64) {
        int idx = base + lane;
        unsigned int ev = (idx < deg) ? ep32[start + idx] : 0u;
        int cnt = min(64, deg - base);
        #pragma unroll
        for (int k4 = 0; k4 < 4; ++k4) {
            int jb = k4 * 16 + g * 4;        // this group's 4 edges this round
            // shfls executed by ALL lanes, unconditionally
            unsigned int eA = (unsigned int)__shfl((int)ev, jb + 0, 64);
            unsigned int eB = (unsigned int)__shfl((int)ev, jb + 1, 64);
            unsigned int eC = (unsigned int)__shfl((int)ev, jb + 2, 64);
            unsigned int eD = (unsigned int)__shfl((int)ev, jb + 3, 64);
            bool okA = jb + 0 < cnt, okB = jb + 1 < cnt;
            bool okC = jb + 2 < cnt, okD = jb + 3 < cnt;
            uint4 vA, vB, vC, vD;
            if (okA) vA = xs4[(size_t)(eA >> 16) * 16 + sl];
            if (okB) vB = xs4[(size_t)(eB >> 16) * 16 + sl];
            if (okC) vC = xs4[(size_t)(eC >> 16) * 16 + sl];
            if (okD) vD = xs4[(size_t)(eD >> 16) * 16 + sl];
            if (okA) {
                float w = (float)(eA & 0xFFFFu) * (1.0f / 65536.0f);
                a0[0] += w * bflo(vA.x); a0[1] += w * bfhi(vA.x);
                a0[2] += w * bflo(vA.y); a0[3] += w * bfhi(vA.y);
                a0[4] += w * bflo(vA.z); a0[5] += w * bfhi(vA.z);
                a0[6] += w * bflo(vA.w); a0[7] += w * bfhi(vA.w);
            }
            if (okB) {
                float w = (float)(eB & 0xFFFFu) * (1.0f / 65536.0f);
                a1[0] += w * bflo(vB.x); a1[1] += w * bfhi(vB.x);
                a1[2] += w * bflo(vB.y); a1[3] += w * bfhi(vB.y);
                a1[4] += w * bflo(vB.z); a1[5] += w * bfhi(vB.z);
                a1[6] += w * bflo(vB.w); a1[7] += w * bfhi(vB.w);
            }
            if (okC) {
                float w = (float)(eC & 0xFFFFu) * (1.0f / 65536.0f);
                a0[0] += w * bflo(vC.x); a0[1] += w * bfhi(vC.x);
                a0[2] += w * bflo(vC.y); a0[3] += w * bfhi(vC.y);
                a0[4] += w * bflo(vC.z); a0[5] += w * bfhi(vC.z);
                a0[6] += w * bflo(vC.w); a0[7] += w * bfhi(vC.w);
            }
            if (okD) {
                float w = (float)(eD & 0xFFFFu) * (1.0f / 65536.0f);
                a1[0] += w * bflo(vD.x); a1[1] += w * bfhi(vD.x);
                a1[2] += w * bflo(vD.y); a1[3] += w * bfhi(vD.y);
                a1[4] += w * bflo(vD.z); a1[5] += w * bfhi(vD.z);
                a1[6] += w * bflo(vD.w); a1[7] += w * bfhi(vD.w);
            }
        }
    }
    #pragma unroll
    for (int f = 0; f < 8; ++f) {
        float v = a0[f] + a1[f];
        v += __shfl_xor(v, 16, 64);
        v += __shfl_xor(v, 32, 64);
        a0[f] = v;
    }
    if (lane < 16) {
        float di = dinv[c];
        uint4 o;
        o.x = f2bf_rn(di * a0[0]) | (f2bf_rn(di * a0[1]) << 16);
        o.y = f2bf_rn(di * a0[2]) | (f2bf_rn(di * a0[3]) << 16);
        o.z = f2bf_rn(di * a0[4]) | (f2bf_rn(di * a0[5]) << 16);
        o.w = f2bf_rn(di * a0[6]) | (f2bf_rn(di * a0[7]) << 16);
        hagg4[(size_t)c * 16 + lane] = o;
    }
}

// ---------- K7: out = relu(hagg @ W) @ Wlin^T + blin  (MFMA, split-bf16 W) ----------
__global__ __launch_bounds__(256) void k_gemm(const uint4* __restrict__ hagg4,
                                              const unsigned short* __restrict__ Wth,
                                              const unsigned short* __restrict__ Wtl,
                                              const float* __restrict__ Wlin,
                                              const float* __restrict__ blin,
                                              float* __restrict__ out, int N) {
    __shared__ __align__(16) unsigned int At[64 * 68];
    __shared__ __align__(16) float WlinL[8 * F];
    int t = threadIdx.x;
    int row0 = blockIdx.x * 64;
    #pragma unroll
    for (int it = 0; it < 4; ++it) {
        int idx = it * 256 + t;          // 1024 uint4 slots
        int rr = idx >> 4, c4 = idx & 15;
        uint4 v = make_uint4(0u, 0u, 0u, 0u);
        if (row0 + rr < N) v = hagg4[(size_t)(row0 + rr) * 16 + c4];
        *(uint4*)&At[rr * 68 + c4 * 4] = v;
    }
    *(float4*)&WlinL[t * 4] = *(const float4*)&Wlin[t * 4];
    __syncthreads();

    int wave = t >> 6, lane = t & 63;
    int sl = lane & 15, q = lane >> 4;
    const unsigned short* Ash = (const unsigned short*)At;
    int mrow = wave * 16 + sl;

    f32x4 acc[8];
    #pragma unroll
    for (int nt = 0; nt < 8; ++nt) acc[nt] = (f32x4){0.f, 0.f, 0.f, 0.f};
    #pragma unroll
    for (int ko = 0; ko < 4; ++ko) {
        bf16x8 a = *(const bf16x8*)&Ash[mrow * 136 + ko * 32 + q * 8];
        #pragma unroll
        for (int nt = 0; nt < 8; ++nt) {
            int boff = (nt * 16 + sl) * F + ko * 32 + q * 8;
            bf16x8 bh = *(const bf16x8*)&Wth[boff];
            bf16x8 bl = *(const bf16x8*)&Wtl[boff];
            acc[nt] = __builtin_amdgcn_mfma_f32_16x16x32_bf16(a, bh, acc[nt], 0, 0, 0);
            acc[nt] = __builtin_amdgcn_mfma_f32_16x16x32_bf16(a, bl, acc[nt], 0, 0, 0);
        }
    }
    #pragma unroll
    for (int nt = 0; nt < 8; ++nt)
        #pragma unroll
        for (int r = 0; r < 4; ++r) acc[nt][r] = fmaxf(acc[nt][r], 0.f);

    float p[8][4];
    #pragma unroll
    for (int tt = 0; tt < 8; ++tt) {
        float wl[8];
        #pragma unroll
        for (int nt = 0; nt < 8; ++nt) wl[nt] = WlinL[tt * F + nt * 16 + sl];
        #pragma unroll
        for (int r = 0; r < 4; ++r) {
            float s = 0.f;
            #pragma unroll
            for (int nt = 0; nt < 8; ++nt) s += acc[nt][r] * wl[nt];
            p[tt][r] = s;
        }
    }
    #pragma unroll
    for (int tt = 0; tt < 8; ++tt)
        #pragma unroll
        for (int r = 0; r < 4; ++r) {
            float v = p[tt][r];
            v += __shfl_xor(v, 1, 64); v += __shfl_xor(v, 2, 64);
            v += __shfl_xor(v, 4, 64); v += __shfl_xor(v, 8, 64);
            p[tt][r] = v;
        }
    if (sl == 0) {
        #pragma unroll
        for (int r = 0; r < 4; ++r) {
            int row = row0 + wave * 16 + q * 4 + r;
            if (row < N) {
                #pragma unroll
                for (int tt = 0; tt < 8; ++tt)
                    out[(size_t)row * 8 + tt] = p[tt][r] + blin[tt];
            }
        }
    }
}

// ---------- launch ----------
extern "C" void kernel_launch(void* const* d_in, const int* in_sizes, int n_in,
                              void* d_out, int out_size, void* d_ws, size_t ws_size,
                              hipStream_t stream) {
    const float* x    = (const float*)d_in[0];
    const int*   ei   = (const int*)d_in[1];
    const float* ew   = (const float*)d_in[2];
    const float* W0   = (const float*)d_in[3];
    const float* Wih  = (const float*)d_in[4];
    const float* Whh  = (const float*)d_in[5];
    const float* bih  = (const float*)d_in[6];
    const float* bhh  = (const float*)d_in[7];
    const float* Wlin = (const float*)d_in[8];
    const float* blin = (const float*)d_in[9];
    int N = in_sizes[0] / F;   // 50000 (must be < 65536 for 4B edge packing)
    int E = in_sizes[1] / 2;   // 800000
    float* outp = (float*)d_out;

    int nblk = (N + 255) / 256;

    char* wsb = (char*)d_ws;
    size_t cur = 0;
    auto alloc = [&](size_t sz) -> void* {
        void* p = wsb + cur;
        cur = (cur + sz + 255) & ~(size_t)255;
        return p;
    };
    unsigned long long* packed = (unsigned long long*)alloc((size_t)N * PSTRIDE * 8);
    float* dinv = (float*)alloc((size_t)N * 4);
    int*   off  = (int*)  alloc((size_t)(N + 1) * 4);
    int*   bsum = (int*)  alloc((size_t)nblk * 4);
    int*   flag = (int*)  alloc(256);
    unsigned short* pos = (unsigned short*)alloc((size_t)E * 2);
    unsigned int* ep32  = (unsigned int*)alloc((size_t)E * 4);
    unsigned short* Wth = (unsigned short*)alloc((size_t)F * F * 2);
    unsigned short* Wtl = (unsigned short*)alloc((size_t)F * F * 2);
    unsigned int* xs    = (unsigned int*)alloc((size_t)N * 64 * 4);
    unsigned int* hagg  = (unsigned int*)alloc((size_t)N * 64 * 4);
    (void)ws_size; (void)n_in; (void)out_size;

    int M  = N * 64;
    int M8 = N * PSTRIDE;
    int nEdgeBlk = (E + 255) / 256;
    int nCastBlk = (M + 255) / 256;

    hipLaunchKernelGGL(k_init,  dim3((M8 + 255) / 256), dim3(256), 0, stream, packed, flag, ei, M8);
    hipLaunchKernelGGL(k_count, dim3(nEdgeBlk),         dim3(256), 0, stream, ei, ew, packed, pos, flag, E);
    hipLaunchKernelGGL(k_bsum,  dim3(nblk),             dim3(256), 0, stream, packed, bsum, N);
    hipLaunchKernelGGL(k_offs2, dim3(nblk),             dim3(256), 0, stream, packed, bsum, off, dinv, N, E);
    hipLaunchKernelGGL(k_ce,    dim3(nCastBlk + F / 2), dim3(256), 0, stream,
                       (const float2*)x, dinv, xs, M, nCastBlk,
                       W0, Wih, Whh, bih, bhh, Wth, Wtl);
    hipLaunchKernelGGL(k_place, dim3(nEdgeBlk),         dim3(256), 0, stream, ei, ew, off, pos, ep32, flag, E);
    hipLaunchKernelGGL(k_agg2,  dim3((N + 3) / 4),      dim3(256), 0, stream,
                       (const uint4*)xs, off, ep32, dinv, (uint4*)hagg, N);
    hipLaunchKernelGGL(k_gemm,  dim3((N + 63) / 64),    dim3(256), 0, stream,
                       (const uint4*)hagg, Wth, Wtl, Wlin, blin, outp, N);
}

// Round 10
// 252.600 us; speedup vs baseline: 1.0698x; 1.0698x over previous
//
#include <hip/hip_runtime.h>
#include <math.h>

#define F 128
#define FIX_SCALE 16777216.0f          // 2^24
#define FIX_INV   (1.0f / 16777216.0f)
#define CNT_SHIFT 40
#define DEG_MASK  ((1ULL << 40) - 1)
#define PSTRIDE 8                      // packed counter stride: 8 ull = 64 B/line

using bf16x8 = __attribute__((ext_vector_type(8))) short;
using f32x4  = __attribute__((ext_vector_type(4))) float;

// ---------- helpers ----------
__device__ inline int read_idx(const int* ei, long long elem, int i64) {
    return i64 ? (int)((const long long*)ei)[elem] : ei[elem];
}
__device__ inline unsigned int f2bf_rn(float f) {   // fp32 -> bf16 bits, RNE
    unsigned int b = __float_as_uint(f);
    return (b + 0x7FFFu + ((b >> 16) & 1u)) >> 16;
}
__device__ inline float bflo(unsigned int u) { return __uint_as_float(u << 16); }
__device__ inline float bfhi(unsigned int u) { return __uint_as_float(u & 0xFFFF0000u); }

// ---------- K1: zero padded packed counters (grid-stride), detect index dtype ----------
__global__ void k_init(unsigned long long* packed, int* flag, const int* ei, int M8) {
    int stride = gridDim.x * blockDim.x;
    for (int i = blockIdx.x * blockDim.x + threadIdx.x; i < M8; i += stride)
        packed[i] = 0ULL;
    if (blockIdx.x == 0 && threadIdx.x == 0) {
        int i64 = 1;
        for (int j = 0; j < 32; ++j) if (ei[2 * j + 1] != 0) { i64 = 0; break; }
        *flag = i64;
    }
}

// ---------- K2: one packed 64-bit atomic per edge (grid-stride) ----------
__global__ void k_count(const int* ei, const float* ew, unsigned long long* packed,
                        unsigned short* pos, const int* flag, int E) {
    int i64 = *flag;
    int stride = gridDim.x * blockDim.x;
    for (int e = blockIdx.x * blockDim.x + threadIdx.x; e < E; e += stride) {
        int c = read_idx(ei, (long long)E + e, i64);
        unsigned long long u = (1ULL << CNT_SHIFT) |
                               (unsigned long long)(ew[e] * FIX_SCALE + 0.5f);
        unsigned long long old = atomicAdd(&packed[(size_t)c * PSTRIDE], u);
        pos[e] = (unsigned short)(old >> CNT_SHIFT);
    }
}

// ---------- K3a: per-block sums of cnt ----------
__global__ void k_bsum(const unsigned long long* __restrict__ packed,
                       int* __restrict__ bsum, int N) {
    __shared__ int s[4];
    int i = blockIdx.x * 256 + threadIdx.x;
    int v = (i < N) ? (int)(packed[(size_t)i * PSTRIDE] >> CNT_SHIFT) : 0;
    #pragma unroll
    for (int o = 1; o < 64; o <<= 1) v += __shfl_xor(v, o, 64);
    if ((threadIdx.x & 63) == 0) s[threadIdx.x >> 6] = v;
    __syncthreads();
    if (threadIdx.x == 0) bsum[blockIdx.x] = s[0] + s[1] + s[2] + s[3];
}

// ---------- K3b: off = exclusive CSR offsets (self-prefixed); dinv = rsqrt(1+deg) ----------
__global__ void k_offs2(const unsigned long long* __restrict__ packed,
                        const int* __restrict__ bsum,
                        int* __restrict__ off, float* __restrict__ dinv, int N, int E) {
    __shared__ int sred[256];
    __shared__ int sdata[256];
    int t = threadIdx.x;
    int pre = 0;
    for (int j = t; j < blockIdx.x; j += 256) pre += bsum[j];
    sred[t] = pre;
    __syncthreads();
    #pragma unroll
    for (int s = 128; s > 0; s >>= 1) {
        if (t < s) sred[t] += sred[t + s];
        __syncthreads();
    }
    int base = sred[0];
    int i = blockIdx.x * 256 + t;
    unsigned long long p = (i < N) ? packed[(size_t)i * PSTRIDE] : 0ULL;
    int v = (int)(p >> CNT_SHIFT);
    sdata[t] = v;
    __syncthreads();
    #pragma unroll
    for (int s = 1; s < 256; s <<= 1) {
        int add = (t >= s) ? sdata[t - s] : 0;
        __syncthreads();
        sdata[t] += add;
        __syncthreads();
    }
    if (i < N) {
        off[i] = base + sdata[t] - v;  // exclusive
        float deg = 1.0f + (float)(p & DEG_MASK) * FIX_INV;  // +1 self-loop
        dinv[i] = rsqrtf(deg);
        if (i == N - 1) off[N] = E;
    }
}

// ---------- K4: xs = bf16(dinv*x), float4 in / uint2 out, grid-stride ----------
__global__ void k_cast(const float4* __restrict__ x4, const float* __restrict__ dinv,
                       uint2* __restrict__ xs2, int M2 /* N*32 */) {
    int stride = gridDim.x * blockDim.x;
    for (int id = blockIdx.x * blockDim.x + threadIdx.x; id < M2; id += stride) {
        float di = dinv[id >> 5];
        float4 v = x4[id];
        xs2[id] = make_uint2(f2bf_rn(di * v.x) | (f2bf_rn(di * v.y) << 16),
                             f2bf_rn(di * v.z) | (f2bf_rn(di * v.w) << 16));
    }
}

// ---------- K5: GRU weight evolution -> transposed split-bf16 W (64 blocks) ----------
__global__ __launch_bounds__(256) void k_evolve(
        const float* __restrict__ W0, const float* __restrict__ Wih,
        const float* __restrict__ Whh, const float* __restrict__ bih,
        const float* __restrict__ bhh,
        unsigned short* __restrict__ Wth, unsigned short* __restrict__ Wtl) {
    __shared__ __align__(16) float w0row[2][F];
    int half = threadIdx.x >> 7;
    int i = blockIdx.x * 2 + half;   // k index (row of W)
    int j = threadIdx.x & 127;       // n index (col of W)
    w0row[half][j] = W0[i * F + j];
    __syncthreads();
    float air = 0, aiz = 0, ain = 0, ahr = 0, ahz = 0, ahn = 0;
    const float* ir_p = Wih + (size_t)j * F;
    const float* iz_p = Wih + (size_t)(j + F) * F;
    const float* in_p = Wih + (size_t)(j + 2 * F) * F;
    const float* hr_p = Whh + (size_t)j * F;
    const float* hz_p = Whh + (size_t)(j + F) * F;
    const float* hn_p = Whh + (size_t)(j + 2 * F) * F;
    for (int k = 0; k < F; k += 4) {
        float4 w0 = *(const float4*)&w0row[half][k];
        float4 a;
        a = *(const float4*)&ir_p[k]; air += w0.x*a.x + w0.y*a.y + w0.z*a.z + w0.w*a.w;
        a = *(const float4*)&iz_p[k]; aiz += w0.x*a.x + w0.y*a.y + w0.z*a.z + w0.w*a.w;
        a = *(const float4*)&in_p[k]; ain += w0.x*a.x + w0.y*a.y + w0.z*a.z + w0.w*a.w;
        a = *(const float4*)&hr_p[k]; ahr += w0.x*a.x + w0.y*a.y + w0.z*a.z + w0.w*a.w;
        a = *(const float4*)&hz_p[k]; ahz += w0.x*a.x + w0.y*a.y + w0.z*a.z + w0.w*a.w;
        a = *(const float4*)&hn_p[k]; ahn += w0.x*a.x + w0.y*a.y + w0.z*a.z + w0.w*a.w;
    }
    air += bih[j];         ahr += bhh[j];
    aiz += bih[j + F];     ahz += bhh[j + F];
    ain += bih[j + 2*F];   ahn += bhh[j + 2*F];
    float r = 1.0f / (1.0f + expf(-(air + ahr)));
    float z = 1.0f / (1.0f + expf(-(aiz + ahz)));
    float n = tanhf(ain + r * ahn);
    float w = (1.0f - z) * n + z * w0row[half][j];
    unsigned int hb = f2bf_rn(w);
    float whi = __uint_as_float(hb << 16);
    unsigned int lb = f2bf_rn(w - whi);
    Wth[j * F + i] = (unsigned short)hb;   // transposed: Wt[n][k]
    Wtl[j * F + i] = (unsigned short)lb;
}

// ---------- K6: placement, packed 4B edge = (row<<16)|w16, grid-stride ----------
__global__ void k_place(const int* ei, const float* ew,
                        const int* __restrict__ off,
                        const unsigned short* __restrict__ pos,
                        unsigned int* ep32, const int* flag, int E) {
    int i64 = *flag;
    int stride = gridDim.x * blockDim.x;
    for (int e = blockIdx.x * blockDim.x + threadIdx.x; e < E; e += stride) {
        int r = read_idx(ei, e, i64);
        int c = read_idx(ei, (long long)E + e, i64);
        unsigned int w16 = (unsigned int)(ew[e] * 65536.0f);
        if (w16 > 65535u) w16 = 65535u;
        ep32[off[c] + (int)pos[e]] = ((unsigned int)r << 16) | w16;  // N < 65536
    }
}

// ---------- K7: aggregation, persistent waves, grid-stride over nodes ----------
__global__ __launch_bounds__(256) void k_agg2(const uint4* __restrict__ xs4,
                                              const int* __restrict__ off,
                                              const unsigned int* __restrict__ ep32,
                                              const float* __restrict__ dinv,
                                              uint4* __restrict__ hagg4, int N) {
    int lane = threadIdx.x & 63;
    int g = lane >> 4, sl = lane & 15;
    int gwave = (int)((blockIdx.x * blockDim.x + threadIdx.x) >> 6);
    int nwave = (int)((gridDim.x * blockDim.x) >> 6);

    for (int c = gwave; c < N; c += nwave) {
        int start = off[c], end = off[c + 1];
        int deg = end - start;

        float a0[8] = {0,0,0,0,0,0,0,0}, a1[8] = {0,0,0,0,0,0,0,0};
        if (g == 0) {   // self-loop (raw weight 1)
            uint4 v = xs4[(size_t)c * 16 + sl];
            a0[0] = bflo(v.x); a0[1] = bfhi(v.x);
            a0[2] = bflo(v.y); a0[3] = bfhi(v.y);
            a0[4] = bflo(v.z); a0[5] = bfhi(v.z);
            a0[6] = bflo(v.w); a0[7] = bfhi(v.w);
        }
        for (int base = 0; base < deg; base += 64) {
            int idx = base + lane;
            unsigned int ev = (idx < deg) ? ep32[start + idx] : 0u;
            int cnt = min(64, deg - base);
            #pragma unroll
            for (int k4 = 0; k4 < 4; ++k4) {
                int jb = k4 * 16 + g * 4;
                // shfls executed by ALL lanes unconditionally (uniform participation)
                unsigned int eA = (unsigned int)__shfl((int)ev, jb + 0, 64);
                unsigned int eB = (unsigned int)__shfl((int)ev, jb + 1, 64);
                unsigned int eC = (unsigned int)__shfl((int)ev, jb + 2, 64);
                unsigned int eD = (unsigned int)__shfl((int)ev, jb + 3, 64);
                bool okA = jb + 0 < cnt, okB = jb + 1 < cnt;
                bool okC = jb + 2 < cnt, okD = jb + 3 < cnt;
                uint4 vA, vB, vC, vD;
                if (okA) vA = xs4[(size_t)(eA >> 16) * 16 + sl];
                if (okB) vB = xs4[(size_t)(eB >> 16) * 16 + sl];
                if (okC) vC = xs4[(size_t)(eC >> 16) * 16 + sl];
                if (okD) vD = xs4[(size_t)(eD >> 16) * 16 + sl];
                if (okA) {
                    float w = (float)(eA & 0xFFFFu) * (1.0f / 65536.0f);
                    a0[0] += w * bflo(vA.x); a0[1] += w * bfhi(vA.x);
                    a0[2] += w * bflo(vA.y); a0[3] += w * bfhi(vA.y);
                    a0[4] += w * bflo(vA.z); a0[5] += w * bfhi(vA.z);
                    a0[6] += w * bflo(vA.w); a0[7] += w * bfhi(vA.w);
                }
                if (okB) {
                    float w = (float)(eB & 0xFFFFu) * (1.0f / 65536.0f);
                    a1[0] += w * bflo(vB.x); a1[1] += w * bfhi(vB.x);
                    a1[2] += w * bflo(vB.y); a1[3] += w * bfhi(vB.y);
                    a1[4] += w * bflo(vB.z); a1[5] += w * bfhi(vB.z);
                    a1[6] += w * bflo(vB.w); a1[7] += w * bfhi(vB.w);
                }
                if (okC) {
                    float w = (float)(eC & 0xFFFFu) * (1.0f / 65536.0f);
                    a0[0] += w * bflo(vC.x); a0[1] += w * bfhi(vC.x);
                    a0[2] += w * bflo(vC.y); a0[3] += w * bfhi(vC.y);
                    a0[4] += w * bflo(vC.z); a0[5] += w * bfhi(vC.z);
                    a0[6] += w * bflo(vC.w); a0[7] += w * bfhi(vC.w);
                }
                if (okD) {
                    float w = (float)(eD & 0xFFFFu) * (1.0f / 65536.0f);
                    a1[0] += w * bflo(vD.x); a1[1] += w * bfhi(vD.x);
                    a1[2] += w * bflo(vD.y); a1[3] += w * bfhi(vD.y);
                    a1[4] += w * bflo(vD.z); a1[5] += w * bfhi(vD.z);
                    a1[6] += w * bflo(vD.w); a1[7] += w * bfhi(vD.w);
                }
            }
        }
        #pragma unroll
        for (int f = 0; f < 8; ++f) {
            float v = a0[f] + a1[f];
            v += __shfl_xor(v, 16, 64);
            v += __shfl_xor(v, 32, 64);
            a0[f] = v;
        }
        if (g == 0) {
            float di = dinv[c];
            uint4 o;
            o.x = f2bf_rn(di * a0[0]) | (f2bf_rn(di * a0[1]) << 16);
            o.y = f2bf_rn(di * a0[2]) | (f2bf_rn(di * a0[3]) << 16);
            o.z = f2bf_rn(di * a0[4]) | (f2bf_rn(di * a0[5]) << 16);
            o.w = f2bf_rn(di * a0[6]) | (f2bf_rn(di * a0[7]) << 16);
            hagg4[(size_t)c * 16 + sl] = o;
        }
    }
}

// ---------- K8: out = relu(hagg @ W) @ Wlin^T + blin  (MFMA, split-bf16 W) ----------
__global__ __launch_bounds__(256) void k_gemm(const uint4* __restrict__ hagg4,
                                              const unsigned short* __restrict__ Wth,
                                              const unsigned short* __restrict__ Wtl,
                                              const float* __restrict__ Wlin,
                                              const float* __restrict__ blin,
                                              float* __restrict__ out, int N) {
    __shared__ __align__(16) unsigned int At[64 * 68];
    __shared__ __align__(16) float WlinL[8 * F];
    int t = threadIdx.x;
    int row0 = blockIdx.x * 64;
    #pragma unroll
    for (int it = 0; it < 4; ++it) {
        int idx = it * 256 + t;          // 1024 uint4 slots
        int rr = idx >> 4, c4 = idx & 15;
        uint4 v = make_uint4(0u, 0u, 0u, 0u);
        if (row0 + rr < N) v = hagg4[(size_t)(row0 + rr) * 16 + c4];
        *(uint4*)&At[rr * 68 + c4 * 4] = v;
    }
    *(float4*)&WlinL[t * 4] = *(const float4*)&Wlin[t * 4];
    __syncthreads();

    int wave = t >> 6, lane = t & 63;
    int sl = lane & 15, q = lane >> 4;
    const unsigned short* Ash = (const unsigned short*)At;
    int mrow = wave * 16 + sl;

    f32x4 acc[8];
    #pragma unroll
    for (int nt = 0; nt < 8; ++nt) acc[nt] = (f32x4){0.f, 0.f, 0.f, 0.f};
    #pragma unroll
    for (int ko = 0; ko < 4; ++ko) {
        bf16x8 a = *(const bf16x8*)&Ash[mrow * 136 + ko * 32 + q * 8];
        #pragma unroll
        for (int nt = 0; nt < 8; ++nt) {
            int boff = (nt * 16 + sl) * F + ko * 32 + q * 8;
            bf16x8 bh = *(const bf16x8*)&Wth[boff];
            bf16x8 bl = *(const bf16x8*)&Wtl[boff];
            acc[nt] = __builtin_amdgcn_mfma_f32_16x16x32_bf16(a, bh, acc[nt], 0, 0, 0);
            acc[nt] = __builtin_amdgcn_mfma_f32_16x16x32_bf16(a, bl, acc[nt], 0, 0, 0);
        }
    }
    #pragma unroll
    for (int nt = 0; nt < 8; ++nt)
        #pragma unroll
        for (int r = 0; r < 4; ++r) acc[nt][r] = fmaxf(acc[nt][r], 0.f);

    float p[8][4];
    #pragma unroll
    for (int tt = 0; tt < 8; ++tt) {
        float wl[8];
        #pragma unroll
        for (int nt = 0; nt < 8; ++nt) wl[nt] = WlinL[tt * F + nt * 16 + sl];
        #pragma unroll
        for (int r = 0; r < 4; ++r) {
            float s = 0.f;
            #pragma unroll
            for (int nt = 0; nt < 8; ++nt) s += acc[nt][r] * wl[nt];
            p[tt][r] = s;
        }
    }
    #pragma unroll
    for (int tt = 0; tt < 8; ++tt)
        #pragma unroll
        for (int r = 0; r < 4; ++r) {
            float v = p[tt][r];
            v += __shfl_xor(v, 1, 64); v += __shfl_xor(v, 2, 64);
            v += __shfl_xor(v, 4, 64); v += __shfl_xor(v, 8, 64);
            p[tt][r] = v;
        }
    if (sl == 0) {
        #pragma unroll
        for (int r = 0; r < 4; ++r) {
            int row = row0 + wave * 16 + q * 4 + r;
            if (row < N) {
                #pragma unroll
                for (int tt = 0; tt < 8; ++tt)
                    out[(size_t)row * 8 + tt] = p[tt][r] + blin[tt];
            }
        }
    }
}

// ---------- launch ----------
extern "C" void kernel_launch(void* const* d_in, const int* in_sizes, int n_in,
                              void* d_out, int out_size, void* d_ws, size_t ws_size,
                              hipStream_t stream) {
    const float* x    = (const float*)d_in[0];
    const int*   ei   = (const int*)d_in[1];
    const float* ew   = (const float*)d_in[2];
    const float* W0   = (const float*)d_in[3];
    const float* Wih  = (const float*)d_in[4];
    const float* Whh  = (const float*)d_in[5];
    const float* bih  = (const float*)d_in[6];
    const float* bhh  = (const float*)d_in[7];
    const float* Wlin = (const float*)d_in[8];
    const float* blin = (const float*)d_in[9];
    int N = in_sizes[0] / F;   // 50000 (must be < 65536 for 4B edge packing)
    int E = in_sizes[1] / 2;   // 800000
    float* outp = (float*)d_out;

    int nblk = (N + 255) / 256;

    char* wsb = (char*)d_ws;
    size_t cur = 0;
    auto alloc = [&](size_t sz) -> void* {
        void* p = wsb + cur;
        cur = (cur + sz + 255) & ~(size_t)255;
        return p;
    };
    unsigned long long* packed = (unsigned long long*)alloc((size_t)N * PSTRIDE * 8);
    float* dinv = (float*)alloc((size_t)N * 4);
    int*   off  = (int*)  alloc((size_t)(N + 1) * 4);
    int*   bsum = (int*)  alloc((size_t)nblk * 4);
    int*   flag = (int*)  alloc(256);
    unsigned short* pos = (unsigned short*)alloc((size_t)E * 2);
    unsigned int* ep32  = (unsigned int*)alloc((size_t)E * 4);
    unsigned short* Wth = (unsigned short*)alloc((size_t)F * F * 2);
    unsigned short* Wtl = (unsigned short*)alloc((size_t)F * F * 2);
    unsigned int* xs    = (unsigned int*)alloc((size_t)N * 64 * 4);
    unsigned int* hagg  = (unsigned int*)alloc((size_t)N * 64 * 4);
    (void)ws_size; (void)n_in; (void)out_size;

    int M2 = N * 32;               // float4 units
    int M8 = N * PSTRIDE;

    hipLaunchKernelGGL(k_init,   dim3(512),           dim3(256), 0, stream, packed, flag, ei, M8);
    hipLaunchKernelGGL(k_count,  dim3(1024),          dim3(256), 0, stream, ei, ew, packed, pos, flag, E);
    hipLaunchKernelGGL(k_bsum,   dim3(nblk),          dim3(256), 0, stream, packed, bsum, N);
    hipLaunchKernelGGL(k_offs2,  dim3(nblk),          dim3(256), 0, stream, packed, bsum, off, dinv, N, E);
    hipLaunchKernelGGL(k_cast,   dim3(512),           dim3(256), 0, stream, (const float4*)x, dinv, (uint2*)xs, M2);
    hipLaunchKernelGGL(k_evolve, dim3(F / 2),         dim3(256), 0, stream, W0, Wih, Whh, bih, bhh, Wth, Wtl);
    hipLaunchKernelGGL(k_place,  dim3(1024),          dim3(256), 0, stream, ei, ew, off, pos, ep32, flag, E);
    hipLaunchKernelGGL(k_agg2,   dim3(2048),          dim3(256), 0, stream,
                       (const uint4*)xs, off, ep32, dinv, (uint4*)hagg, N);
    hipLaunchKernelGGL(k_gemm,   dim3((N + 63) / 64), dim3(256), 0, stream,
                       (const uint4*)hagg, Wth, Wtl, Wlin, blin, outp, N);
}